// Round 2
// baseline (1014.565 us; speedup 1.0000x reference)
//
#include <hip/hip_runtime.h>
#include <hip/hip_bf16.h>

#define BB 4
#define NN 4096
#define DD 512
#define BND (BB*NN)   // 16384

// ---------- bf16 helpers ----------
__device__ __forceinline__ float b2f(unsigned int u){
    union { unsigned int u; float f; } c; c.u = u << 16; return c.f;
}
__device__ __forceinline__ unsigned short f2b(float f){
    union { float f; unsigned int u; } c; c.f = f;
    unsigned int r = c.u + 0x7fffu + ((c.u >> 16) & 1u);   // RNE
    return (unsigned short)(r >> 16);
}
__device__ __forceinline__ void unpack8(uint4 v, float* o){
    o[0]=b2f(v.x & 0xffffu); o[1]=b2f(v.x >> 16);
    o[2]=b2f(v.y & 0xffffu); o[3]=b2f(v.y >> 16);
    o[4]=b2f(v.z & 0xffffu); o[5]=b2f(v.z >> 16);
    o[6]=b2f(v.w & 0xffffu); o[7]=b2f(v.w >> 16);
}

// ---------- sin/cos table: idx = pi/2 * (t+1)/N ----------
__global__ void k_sincos(float* __restrict__ sc){
    int t = blockIdx.x * 256 + threadIdx.x;
    if (t < NN){
        float idx = 1.5707963267948966f * ((float)(t + 1) / (float)NN);
        sc[t]      = sinf(idx);
        sc[NN + t] = cosf(idx);
    }
}

// ---------- q,k,v = relu?(x @ W^T); x,W fp32; out stored bf16 ----------
__global__ __launch_bounds__(256) void k_qkv(
    const float* __restrict__ X,
    const float* __restrict__ Wq,
    const float* __restrict__ Wk,
    const float* __restrict__ Wv,
    unsigned short* __restrict__ Q,
    unsigned short* __restrict__ K,
    unsigned short* __restrict__ V)
{
    __shared__ float xs[64][33];
    __shared__ float ws[64][33];
    const int which = blockIdx.z;
    const float*    W = (which == 0) ? Wq : ((which == 1) ? Wk : Wv);
    unsigned short* O = (which == 0) ? Q  : ((which == 1) ? K  : V);

    const int tid = threadIdx.x;
    const int r0 = blockIdx.x * 64;   // row tile in [0, BND)
    const int c0 = blockIdx.y * 64;   // col tile in [0, DD)
    const int tx = tid & 15, ty = tid >> 4;
    const int lrow = tid >> 2, lcol = (tid & 3) * 8;

    float acc[4][4] = {};
    for (int k0 = 0; k0 < DD; k0 += 32){
        const float* xp = X + (size_t)(r0 + lrow) * DD + k0 + lcol;
        const float* wp = W + (size_t)(c0 + lrow) * DD + k0 + lcol;
        float4 xa = *reinterpret_cast<const float4*>(xp);
        float4 xb = *reinterpret_cast<const float4*>(xp + 4);
        float4 wa = *reinterpret_cast<const float4*>(wp);
        float4 wb = *reinterpret_cast<const float4*>(wp + 4);
        *reinterpret_cast<float4*>(&xs[lrow][lcol])     = xa;
        *reinterpret_cast<float4*>(&xs[lrow][lcol + 4]) = xb;
        *reinterpret_cast<float4*>(&ws[lrow][lcol])     = wa;
        *reinterpret_cast<float4*>(&ws[lrow][lcol + 4]) = wb;
        __syncthreads();
        #pragma unroll
        for (int kk = 0; kk < 32; ++kk){
            float a[4], b[4];
            #pragma unroll
            for (int i = 0; i < 4; ++i) a[i] = xs[ty*4+i][kk];
            #pragma unroll
            for (int j = 0; j < 4; ++j) b[j] = ws[tx*4+j][kk];
            #pragma unroll
            for (int i = 0; i < 4; ++i)
                #pragma unroll
                for (int j = 0; j < 4; ++j)
                    acc[i][j] = fmaf(a[i], b[j], acc[i][j]);
        }
        __syncthreads();
    }
    const bool relu = (which < 2);
    #pragma unroll
    for (int i = 0; i < 4; ++i){
        unsigned short pk[4];
        #pragma unroll
        for (int j = 0; j < 4; ++j){
            float v = acc[i][j];
            if (relu) v = fmaxf(v, 0.0f);
            pk[j] = f2b(v);
        }
        uint2 st;
        st.x = (unsigned int)pk[0] | ((unsigned int)pk[1] << 16);
        st.y = (unsigned int)pk[2] | ((unsigned int)pk[3] << 16);
        *reinterpret_cast<uint2*>(O + (size_t)(r0 + ty*4 + i) * DD + c0 + tx*4) = st;
    }
}

// ---------- kv_s[d,m] = sum_n sin_n k[n,d] v[n,m];  kv_c with cos ----------
__global__ __launch_bounds__(256) void k_kv(
    const unsigned short* __restrict__ Kb,
    const unsigned short* __restrict__ Vb,
    const float* __restrict__ sc,
    float* __restrict__ kvs, float* __restrict__ kvc)
{
    __shared__ __align__(16) float ks[32][72];
    __shared__ __align__(16) float vs[32][72];
    __shared__ float shs[32], shc[32];
    const int tid = threadIdx.x;
    const int d0 = blockIdx.x * 64, m0 = blockIdx.y * 64;
    const int b = blockIdx.z >> 2, sp = blockIdx.z & 3;   // split-K over n (4 chunks)
    const int tx = tid & 15, ty = tid >> 4;
    const int lr = tid >> 3, lc = (tid & 7) * 8;

    float as[4][4] = {}, ac[4][4] = {};
    const int nbeg = sp * 1024, nend = nbeg + 1024;
    for (int n0 = nbeg; n0 < nend; n0 += 32){
        uint4 kv4 = *reinterpret_cast<const uint4*>(Kb + ((size_t)b*NN + n0 + lr) * DD + d0 + lc);
        uint4 vv4 = *reinterpret_cast<const uint4*>(Vb + ((size_t)b*NN + n0 + lr) * DD + m0 + lc);
        float kf[8], vf[8]; unpack8(kv4, kf); unpack8(vv4, vf);
        if (tid < 32){ shs[tid] = sc[n0 + tid]; shc[tid] = sc[NN + n0 + tid]; }
        #pragma unroll
        for (int u = 0; u < 8; ++u){ ks[lr][lc+u] = kf[u]; vs[lr][lc+u] = vf[u]; }
        __syncthreads();
        #pragma unroll
        for (int nn = 0; nn < 32; ++nn){
            float s = shs[nn], c = shc[nn];
            float a[4], bv[4], a_s[4], a_c[4];
            #pragma unroll
            for (int i = 0; i < 4; ++i) a[i] = ks[nn][ty*4+i];
            #pragma unroll
            for (int j = 0; j < 4; ++j) bv[j] = vs[nn][tx*4+j];
            #pragma unroll
            for (int i = 0; i < 4; ++i){ a_s[i] = a[i]*s; a_c[i] = a[i]*c; }
            #pragma unroll
            for (int i = 0; i < 4; ++i)
                #pragma unroll
                for (int j = 0; j < 4; ++j){
                    as[i][j] = fmaf(a_s[i], bv[j], as[i][j]);
                    ac[i][j] = fmaf(a_c[i], bv[j], ac[i][j]);
                }
        }
        __syncthreads();
    }
    #pragma unroll
    for (int i = 0; i < 4; ++i)
        #pragma unroll
        for (int j = 0; j < 4; ++j){
            size_t idx = ((size_t)b*DD + d0 + ty*4 + i) * DD + m0 + tx*4 + j;
            atomicAdd(&kvs[idx], as[i][j]);
            atomicAdd(&kvc[idx], ac[i][j]);
        }
}

// ---------- ksum_{s,c}[b,d] = sum_n w_n k[b,n,d] ----------
__global__ void k_ksum(const unsigned short* __restrict__ Kb,
                       const float* __restrict__ sc, float* __restrict__ ksum)
{
    int b = blockIdx.x, dc = blockIdx.y, sp = blockIdx.z;
    int d = dc * 256 + threadIdx.x;
    float ss = 0.f, cc = 0.f;
    int n0 = sp * 128;
    for (int n = n0; n < n0 + 128; ++n){
        float kvv = b2f((unsigned int)Kb[((size_t)b*NN + n) * DD + d]);
        ss = fmaf(kvv, sc[n], ss);
        cc = fmaf(kvv, sc[NN + n], cc);
    }
    atomicAdd(&ksum[(size_t)b*2*DD + d], ss);
    atomicAdd(&ksum[(size_t)b*2*DD + DD + d], cc);
}

// ---------- z[b,n] = 1/max(sin_n*(q.ksum_s) + cos_n*(q.ksum_c), 1e-6) ----------
__global__ __launch_bounds__(256) void k_z(
    const unsigned short* __restrict__ Qb,
    const float* __restrict__ ksum, const float* __restrict__ sc,
    float* __restrict__ zden)
{
    int row  = blockIdx.x * 4 + (threadIdx.x >> 6);   // global row [0, BND)
    int lane = threadIdx.x & 63;
    int b = row >> 12, n = row & (NN - 1);
    uint4 qv = *reinterpret_cast<const uint4*>(Qb + (size_t)row * DD + lane * 8);
    float qf[8]; unpack8(qv, qf);
    const float* kss = ksum + (size_t)b*2*DD + lane*8;
    const float* ksc = kss + DD;
    float ps = 0.f, pc = 0.f;
    #pragma unroll
    for (int u = 0; u < 8; ++u){ ps = fmaf(qf[u], kss[u], ps); pc = fmaf(qf[u], ksc[u], pc); }
    #pragma unroll
    for (int off = 32; off; off >>= 1){ ps += __shfl_xor(ps, off); pc += __shfl_xor(pc, off); }
    if (lane == 0){
        float den = sc[n]*ps + sc[NN+n]*pc;
        zden[row] = 1.0f / fmaxf(den, 1e-6f);
    }
}

// ---------- out = (sin*q@kvs + cos*q@kvc)*z, scrambled fp32 write ----------
__global__ __launch_bounds__(256) void k_out(
    const unsigned short* __restrict__ Qb,
    const float* __restrict__ kvs, const float* __restrict__ kvc,
    const float* __restrict__ zden, const float* __restrict__ sc,
    float* __restrict__ Out)
{
    __shared__ float qs[64][33];
    __shared__ __align__(16) float bs[32][72];
    __shared__ __align__(16) float bc[32][72];
    const int tid = threadIdx.x;
    const int r0 = blockIdx.x * 64, m0 = blockIdx.y * 64;
    const int b = r0 >> 12;
    const int tx = tid & 15, ty = tid >> 4;
    const int lrow = tid >> 2, lcol = (tid & 3) * 8;   // q tile 64x32
    const int br = tid >> 3, bcl = (tid & 7) * 8;      // kv tiles 32x64

    float accs[4][4] = {}, accc[4][4] = {};
    for (int k0 = 0; k0 < DD; k0 += 32){
        uint4 qv = *reinterpret_cast<const uint4*>(Qb + (size_t)(r0 + lrow) * DD + k0 + lcol);
        float qf[8]; unpack8(qv, qf);
        const float* srcS = kvs + ((size_t)b*DD + k0 + br) * DD + m0 + bcl;
        const float* srcC = kvc + ((size_t)b*DD + k0 + br) * DD + m0 + bcl;
        float4 s0 = *reinterpret_cast<const float4*>(srcS);
        float4 s1 = *reinterpret_cast<const float4*>(srcS + 4);
        float4 c0 = *reinterpret_cast<const float4*>(srcC);
        float4 c1 = *reinterpret_cast<const float4*>(srcC + 4);
        #pragma unroll
        for (int u = 0; u < 8; ++u) qs[lrow][lcol+u] = qf[u];
        *reinterpret_cast<float4*>(&bs[br][bcl])     = s0;
        *reinterpret_cast<float4*>(&bs[br][bcl + 4]) = s1;
        *reinterpret_cast<float4*>(&bc[br][bcl])     = c0;
        *reinterpret_cast<float4*>(&bc[br][bcl + 4]) = c1;
        __syncthreads();
        #pragma unroll
        for (int kk = 0; kk < 32; ++kk){
            float a[4], sb[4], cb[4];
            #pragma unroll
            for (int i = 0; i < 4; ++i) a[i] = qs[ty*4+i][kk];
            #pragma unroll
            for (int j = 0; j < 4; ++j){ sb[j] = bs[kk][tx*4+j]; cb[j] = bc[kk][tx*4+j]; }
            #pragma unroll
            for (int i = 0; i < 4; ++i)
                #pragma unroll
                for (int j = 0; j < 4; ++j){
                    accs[i][j] = fmaf(a[i], sb[j], accs[i][j]);
                    accc[i][j] = fmaf(a[i], cb[j], accc[i][j]);
                }
        }
        __syncthreads();
    }
    #pragma unroll
    for (int i = 0; i < 4; ++i){
        int grow = r0 + ty*4 + i;
        int n = grow & (NN - 1);
        float z  = zden[grow];
        float sn = sc[n], cn = sc[NN + n];
        int hh = n >> 9;
        int tt = (n & 511) * 8 + (m0 >> 6);
        float4 st;
        st.x = (sn*accs[i][0] + cn*accc[i][0]) * z;
        st.y = (sn*accs[i][1] + cn*accc[i][1]) * z;
        st.z = (sn*accs[i][2] + cn*accc[i][2]) * z;
        st.w = (sn*accs[i][3] + cn*accc[i][3]) * z;
        *reinterpret_cast<float4*>(Out + ((size_t)b*NN + tt) * DD + hh*64 + tx*4) = st;
    }
}

extern "C" void kernel_launch(void* const* d_in, const int* in_sizes, int n_in,
                              void* d_out, int out_size, void* d_ws, size_t ws_size,
                              hipStream_t stream)
{
    const float* X  = (const float*)d_in[0];
    const float* Wq = (const float*)d_in[1];
    const float* Wk = (const float*)d_in[2];
    const float* Wv = (const float*)d_in[3];
    float* Out = (float*)d_out;

    char* p = (char*)d_ws;
    float* sincos = (float*)p; p += (size_t)2*NN*sizeof(float);
    float* kvs    = (float*)p; p += (size_t)BB*DD*DD*sizeof(float);
    float* kvc    = (float*)p; p += (size_t)BB*DD*DD*sizeof(float);
    float* ksum   = (float*)p; p += (size_t)BB*2*DD*sizeof(float);
    float* zden   = (float*)p; p += (size_t)BND*sizeof(float);
    unsigned short* Qb = (unsigned short*)p; p += (size_t)BND*DD*2;
    unsigned short* Kb = (unsigned short*)p; p += (size_t)BND*DD*2;
    unsigned short* Vb = (unsigned short*)p; p += (size_t)BND*DD*2;

    // kvs, kvc, ksum are contiguous -> one async memset (graph-capture safe)
    hipMemsetAsync(kvs, 0, ((size_t)2*BB*DD*DD + (size_t)BB*2*DD) * sizeof(float), stream);

    k_sincos<<<dim3((NN + 255) / 256), dim3(256), 0, stream>>>(sincos);
    k_qkv  <<<dim3(BND/64, DD/64, 3), dim3(256), 0, stream>>>(X, Wq, Wk, Wv, Qb, Kb, Vb);
    k_kv   <<<dim3(DD/64, DD/64, BB*4), dim3(256), 0, stream>>>(Kb, Vb, sincos, kvs, kvc);
    k_ksum <<<dim3(BB, DD/256, 32), dim3(256), 0, stream>>>(Kb, sincos, ksum);
    k_z    <<<dim3(BND/4), dim3(256), 0, stream>>>(Qb, ksum, sincos, zden);
    k_out  <<<dim3(BND/64, DD/64), dim3(256), 0, stream>>>(Qb, kvs, kvc, zden, sincos, Out);
}

// Round 3
// 588.492 us; speedup vs baseline: 1.7240x; 1.7240x over previous
//
#include <hip/hip_runtime.h>
#include <hip/hip_bf16.h>

#define BB 4
#define NN 4096
#define DD 512
#define BND (BB*NN)   // 16384

typedef __attribute__((ext_vector_type(8))) short bf16x8;
typedef __attribute__((ext_vector_type(4))) float f32x4;

// ---------- bf16 helpers ----------
__device__ __forceinline__ float b2f(unsigned int u){
    union { unsigned int u; float f; } c; c.u = u << 16; return c.f;
}
__device__ __forceinline__ unsigned short f2b(float f){
    union { float f; unsigned int u; } c; c.f = f;
    unsigned int r = c.u + 0x7fffu + ((c.u >> 16) & 1u);   // RNE
    return (unsigned short)(r >> 16);
}
__device__ __forceinline__ unsigned int pack2(float lo, float hi){
    __hip_bfloat162 h = __float22bfloat162_rn(make_float2(lo, hi));
    return *reinterpret_cast<unsigned int*>(&h);
}
__device__ __forceinline__ void unpack8(uint4 v, float* o){
    o[0]=b2f(v.x & 0xffffu); o[1]=b2f(v.x >> 16);
    o[2]=b2f(v.y & 0xffffu); o[3]=b2f(v.y >> 16);
    o[4]=b2f(v.z & 0xffffu); o[5]=b2f(v.z >> 16);
    o[6]=b2f(v.w & 0xffffu); o[7]=b2f(v.w >> 16);
}

// ---------- sin/cos table: idx = pi/2 * (t+1)/N ----------
__global__ void k_sincos(float* __restrict__ sc){
    int t = blockIdx.x * 256 + threadIdx.x;
    if (t < NN){
        float idx = 1.5707963267948966f * ((float)(t + 1) / (float)NN);
        sc[t]      = sinf(idx);
        sc[NN + t] = cosf(idx);
    }
}

// ---------- q,k,v = relu?(x @ W^T) via MFMA bf16; x,W fp32; out bf16 ----------
// 128x128 tile, 4 waves (2x2), each wave 64x64 = 4x4 frags of 16x16x32, BK=32.
__global__ __launch_bounds__(256) void k_qkv_mfma(
    const float* __restrict__ X,
    const float* __restrict__ Wq,
    const float* __restrict__ Wk,
    const float* __restrict__ Wv,
    unsigned short* __restrict__ Q,
    unsigned short* __restrict__ K,
    unsigned short* __restrict__ V)
{
    __shared__ __align__(16) unsigned short As[128][40];  // +8 pad: stride 80B, <=2-way banks
    __shared__ __align__(16) unsigned short Bs[128][40];

    const int which = blockIdx.z;
    const float*    W = (which == 0) ? Wq : ((which == 1) ? Wk : Wv);
    unsigned short* O = (which == 0) ? Q  : ((which == 1) ? K  : V);

    const int tid = threadIdx.x;
    const int r0 = blockIdx.x * 128;          // rows of X
    const int c0 = blockIdx.y * 128;          // rows of W (= output cols)
    const int w  = tid >> 6;
    const int l  = tid & 63;
    const int wrow = (w >> 1) * 64;
    const int wcol = (w & 1) * 64;
    const int lm = l & 15;
    const int lk = (l >> 4) * 8;

    // staging: thread t covers rows (t>>2) and (t>>2)+64, cols (t&3)*8 .. +7
    const int srow = tid >> 2;
    const int scol = (tid & 3) * 8;
    const float* xp0 = X + (size_t)(r0 + srow) * DD + scol;
    const float* wp0 = W + (size_t)(c0 + srow) * DD + scol;

    f32x4 acc[4][4];
    #pragma unroll
    for (int i = 0; i < 4; ++i)
        #pragma unroll
        for (int j = 0; j < 4; ++j)
            #pragma unroll
            for (int q = 0; q < 4; ++q)
                acc[i][j][q] = 0.0f;

    for (int k0 = 0; k0 < DD; k0 += 32){
        const float* xa = xp0 + k0;
        float4 a0 = *reinterpret_cast<const float4*>(xa);
        float4 a1 = *reinterpret_cast<const float4*>(xa + 4);
        float4 a2 = *reinterpret_cast<const float4*>(xa + (size_t)64*DD);
        float4 a3 = *reinterpret_cast<const float4*>(xa + (size_t)64*DD + 4);
        const float* wa = wp0 + k0;
        float4 b0 = *reinterpret_cast<const float4*>(wa);
        float4 b1 = *reinterpret_cast<const float4*>(wa + 4);
        float4 b2 = *reinterpret_cast<const float4*>(wa + (size_t)64*DD);
        float4 b3 = *reinterpret_cast<const float4*>(wa + (size_t)64*DD + 4);
        __syncthreads();   // previous iter's ds_reads done before overwrite
        uint4 st;
        st.x = pack2(a0.x, a0.y); st.y = pack2(a0.z, a0.w);
        st.z = pack2(a1.x, a1.y); st.w = pack2(a1.z, a1.w);
        *reinterpret_cast<uint4*>(&As[srow][scol]) = st;
        st.x = pack2(a2.x, a2.y); st.y = pack2(a2.z, a2.w);
        st.z = pack2(a3.x, a3.y); st.w = pack2(a3.z, a3.w);
        *reinterpret_cast<uint4*>(&As[srow + 64][scol]) = st;
        st.x = pack2(b0.x, b0.y); st.y = pack2(b0.z, b0.w);
        st.z = pack2(b1.x, b1.y); st.w = pack2(b1.z, b1.w);
        *reinterpret_cast<uint4*>(&Bs[srow][scol]) = st;
        st.x = pack2(b2.x, b2.y); st.y = pack2(b2.z, b2.w);
        st.z = pack2(b3.x, b3.y); st.w = pack2(b3.z, b3.w);
        *reinterpret_cast<uint4*>(&Bs[srow + 64][scol]) = st;
        __syncthreads();

        bf16x8 af[4], bfr[4];
        #pragma unroll
        for (int i = 0; i < 4; ++i)
            af[i] = *reinterpret_cast<const bf16x8*>(&As[wrow + i*16 + lm][lk]);
        #pragma unroll
        for (int j = 0; j < 4; ++j)
            bfr[j] = *reinterpret_cast<const bf16x8*>(&Bs[wcol + j*16 + lm][lk]);
        #pragma unroll
        for (int i = 0; i < 4; ++i)
            #pragma unroll
            for (int j = 0; j < 4; ++j)
                acc[i][j] = __builtin_amdgcn_mfma_f32_16x16x32_bf16(af[i], bfr[j], acc[i][j], 0, 0, 0);
    }

    const bool relu = (which < 2);
    #pragma unroll
    for (int i = 0; i < 4; ++i){
        #pragma unroll
        for (int q = 0; q < 4; ++q){
            int row = r0 + wrow + i*16 + (l >> 4)*4 + q;
            size_t base = (size_t)row * DD + c0 + wcol + lm;
            #pragma unroll
            for (int j = 0; j < 4; ++j){
                float v = acc[i][j][q];
                if (relu) v = fmaxf(v, 0.0f);
                O[base + j*16] = f2b(v);
            }
        }
    }
}

// ---------- kv_s[d,m] = sum_n sin_n k[n,d] v[n,m];  kv_c with cos ----------
__global__ __launch_bounds__(256) void k_kv(
    const unsigned short* __restrict__ Kb,
    const unsigned short* __restrict__ Vb,
    const float* __restrict__ sc,
    float* __restrict__ kvs, float* __restrict__ kvc)
{
    __shared__ __align__(16) float ks[32][72];
    __shared__ __align__(16) float vs[32][72];
    __shared__ float shs[32], shc[32];
    const int tid = threadIdx.x;
    const int d0 = blockIdx.x * 64, m0 = blockIdx.y * 64;
    const int b = blockIdx.z >> 2, sp = blockIdx.z & 3;   // split-K over n (4 chunks)
    const int tx = tid & 15, ty = tid >> 4;
    const int lr = tid >> 3, lc = (tid & 7) * 8;

    float as[4][4] = {}, ac[4][4] = {};
    const int nbeg = sp * 1024, nend = nbeg + 1024;
    for (int n0 = nbeg; n0 < nend; n0 += 32){
        uint4 kv4 = *reinterpret_cast<const uint4*>(Kb + ((size_t)b*NN + n0 + lr) * DD + d0 + lc);
        uint4 vv4 = *reinterpret_cast<const uint4*>(Vb + ((size_t)b*NN + n0 + lr) * DD + m0 + lc);
        float kf[8], vf[8]; unpack8(kv4, kf); unpack8(vv4, vf);
        if (tid < 32){ shs[tid] = sc[n0 + tid]; shc[tid] = sc[NN + n0 + tid]; }
        #pragma unroll
        for (int u = 0; u < 8; ++u){ ks[lr][lc+u] = kf[u]; vs[lr][lc+u] = vf[u]; }
        __syncthreads();
        #pragma unroll
        for (int nn = 0; nn < 32; ++nn){
            float s = shs[nn], c = shc[nn];
            float a[4], bv[4], a_s[4], a_c[4];
            #pragma unroll
            for (int i = 0; i < 4; ++i) a[i] = ks[nn][ty*4+i];
            #pragma unroll
            for (int j = 0; j < 4; ++j) bv[j] = vs[nn][tx*4+j];
            #pragma unroll
            for (int i = 0; i < 4; ++i){ a_s[i] = a[i]*s; a_c[i] = a[i]*c; }
            #pragma unroll
            for (int i = 0; i < 4; ++i)
                #pragma unroll
                for (int j = 0; j < 4; ++j){
                    as[i][j] = fmaf(a_s[i], bv[j], as[i][j]);
                    ac[i][j] = fmaf(a_c[i], bv[j], ac[i][j]);
                }
        }
        __syncthreads();
    }
    #pragma unroll
    for (int i = 0; i < 4; ++i)
        #pragma unroll
        for (int j = 0; j < 4; ++j){
            size_t idx = ((size_t)b*DD + d0 + ty*4 + i) * DD + m0 + tx*4 + j;
            atomicAdd(&kvs[idx], as[i][j]);
            atomicAdd(&kvc[idx], ac[i][j]);
        }
}

// ---------- ksum_{s,c}[b,d] = sum_n w_n k[b,n,d] ----------
__global__ void k_ksum(const unsigned short* __restrict__ Kb,
                       const float* __restrict__ sc, float* __restrict__ ksum)
{
    int b = blockIdx.x, dc = blockIdx.y, sp = blockIdx.z;
    int d = dc * 256 + threadIdx.x;
    float ss = 0.f, cc = 0.f;
    int n0 = sp * 128;
    for (int n = n0; n < n0 + 128; ++n){
        float kvv = b2f((unsigned int)Kb[((size_t)b*NN + n) * DD + d]);
        ss = fmaf(kvv, sc[n], ss);
        cc = fmaf(kvv, sc[NN + n], cc);
    }
    atomicAdd(&ksum[(size_t)b*2*DD + d], ss);
    atomicAdd(&ksum[(size_t)b*2*DD + DD + d], cc);
}

// ---------- z[b,n] = 1/max(sin_n*(q.ksum_s) + cos_n*(q.ksum_c), 1e-6) ----------
__global__ __launch_bounds__(256) void k_z(
    const unsigned short* __restrict__ Qb,
    const float* __restrict__ ksum, const float* __restrict__ sc,
    float* __restrict__ zden)
{
    int row  = blockIdx.x * 4 + (threadIdx.x >> 6);   // global row [0, BND)
    int lane = threadIdx.x & 63;
    int b = row >> 12, n = row & (NN - 1);
    uint4 qv = *reinterpret_cast<const uint4*>(Qb + (size_t)row * DD + lane * 8);
    float qf[8]; unpack8(qv, qf);
    const float* kss = ksum + (size_t)b*2*DD + lane*8;
    const float* ksc = kss + DD;
    float ps = 0.f, pc = 0.f;
    #pragma unroll
    for (int u = 0; u < 8; ++u){ ps = fmaf(qf[u], kss[u], ps); pc = fmaf(qf[u], ksc[u], pc); }
    #pragma unroll
    for (int off = 32; off; off >>= 1){ ps += __shfl_xor(ps, off); pc += __shfl_xor(pc, off); }
    if (lane == 0){
        float den = sc[n]*ps + sc[NN+n]*pc;
        zden[row] = 1.0f / fmaxf(den, 1e-6f);
    }
}

// ---------- out = (sin*q@kvs + cos*q@kvc)*z, scrambled fp32 write ----------
__global__ __launch_bounds__(256) void k_out(
    const unsigned short* __restrict__ Qb,
    const float* __restrict__ kvs, const float* __restrict__ kvc,
    const float* __restrict__ zden, const float* __restrict__ sc,
    float* __restrict__ Out)
{
    __shared__ float qs[64][33];
    __shared__ __align__(16) float bs[32][72];
    __shared__ __align__(16) float bc[32][72];
    const int tid = threadIdx.x;
    const int r0 = blockIdx.x * 64, m0 = blockIdx.y * 64;
    const int b = r0 >> 12;
    const int tx = tid & 15, ty = tid >> 4;
    const int lrow = tid >> 2, lcol = (tid & 3) * 8;   // q tile 64x32
    const int br = tid >> 3, bcl = (tid & 7) * 8;      // kv tiles 32x64

    float accs[4][4] = {}, accc[4][4] = {};
    for (int k0 = 0; k0 < DD; k0 += 32){
        uint4 qv = *reinterpret_cast<const uint4*>(Qb + (size_t)(r0 + lrow) * DD + k0 + lcol);
        float qf[8]; unpack8(qv, qf);
        const float* srcS = kvs + ((size_t)b*DD + k0 + br) * DD + m0 + bcl;
        const float* srcC = kvc + ((size_t)b*DD + k0 + br) * DD + m0 + bcl;
        float4 s0 = *reinterpret_cast<const float4*>(srcS);
        float4 s1 = *reinterpret_cast<const float4*>(srcS + 4);
        float4 c0 = *reinterpret_cast<const float4*>(srcC);
        float4 c1 = *reinterpret_cast<const float4*>(srcC + 4);
        #pragma unroll
        for (int u = 0; u < 8; ++u) qs[lrow][lcol+u] = qf[u];
        *reinterpret_cast<float4*>(&bs[br][bcl])     = s0;
        *reinterpret_cast<float4*>(&bs[br][bcl + 4]) = s1;
        *reinterpret_cast<float4*>(&bc[br][bcl])     = c0;
        *reinterpret_cast<float4*>(&bc[br][bcl + 4]) = c1;
        __syncthreads();
        #pragma unroll
        for (int kk = 0; kk < 32; ++kk){
            float a[4], sb[4], cb[4];
            #pragma unroll
            for (int i = 0; i < 4; ++i) a[i] = qs[ty*4+i][kk];
            #pragma unroll
            for (int j = 0; j < 4; ++j){ sb[j] = bs[kk][tx*4+j]; cb[j] = bc[kk][tx*4+j]; }
            #pragma unroll
            for (int i = 0; i < 4; ++i)
                #pragma unroll
                for (int j = 0; j < 4; ++j){
                    accs[i][j] = fmaf(a[i], sb[j], accs[i][j]);
                    accc[i][j] = fmaf(a[i], cb[j], accc[i][j]);
                }
        }
        __syncthreads();
    }
    #pragma unroll
    for (int i = 0; i < 4; ++i){
        int grow = r0 + ty*4 + i;
        int n = grow & (NN - 1);
        float z  = zden[grow];
        float sn = sc[n], cn = sc[NN + n];
        int hh = n >> 9;
        int tt = (n & 511) * 8 + (m0 >> 6);
        float4 st;
        st.x = (sn*accs[i][0] + cn*accc[i][0]) * z;
        st.y = (sn*accs[i][1] + cn*accc[i][1]) * z;
        st.z = (sn*accs[i][2] + cn*accc[i][2]) * z;
        st.w = (sn*accs[i][3] + cn*accc[i][3]) * z;
        *reinterpret_cast<float4*>(Out + ((size_t)b*NN + tt) * DD + hh*64 + tx*4) = st;
    }
}

extern "C" void kernel_launch(void* const* d_in, const int* in_sizes, int n_in,
                              void* d_out, int out_size, void* d_ws, size_t ws_size,
                              hipStream_t stream)
{
    const float* X  = (const float*)d_in[0];
    const float* Wq = (const float*)d_in[1];
    const float* Wk = (const float*)d_in[2];
    const float* Wv = (const float*)d_in[3];
    float* Out = (float*)d_out;

    char* p = (char*)d_ws;
    float* sincos = (float*)p; p += (size_t)2*NN*sizeof(float);
    float* kvs    = (float*)p; p += (size_t)BB*DD*DD*sizeof(float);
    float* kvc    = (float*)p; p += (size_t)BB*DD*DD*sizeof(float);
    float* ksum   = (float*)p; p += (size_t)BB*2*DD*sizeof(float);
    float* zden   = (float*)p; p += (size_t)BND*sizeof(float);
    unsigned short* Qb = (unsigned short*)p; p += (size_t)BND*DD*2;
    unsigned short* Kb = (unsigned short*)p; p += (size_t)BND*DD*2;
    unsigned short* Vb = (unsigned short*)p; p += (size_t)BND*DD*2;

    // kvs, kvc, ksum are contiguous -> one async memset (graph-capture safe)
    hipMemsetAsync(kvs, 0, ((size_t)2*BB*DD*DD + (size_t)BB*2*DD) * sizeof(float), stream);

    k_sincos  <<<dim3((NN + 255) / 256), dim3(256), 0, stream>>>(sincos);
    k_qkv_mfma<<<dim3(BND/128, DD/128, 3), dim3(256), 0, stream>>>(X, Wq, Wk, Wv, Qb, Kb, Vb);
    k_kv      <<<dim3(DD/64, DD/64, BB*4), dim3(256), 0, stream>>>(Kb, Vb, sincos, kvs, kvc);
    k_ksum    <<<dim3(BB, DD/256, 32), dim3(256), 0, stream>>>(Kb, sincos, ksum);
    k_z       <<<dim3(BND/4), dim3(256), 0, stream>>>(Qb, ksum, sincos, zden);
    k_out     <<<dim3(BND/64, DD/64), dim3(256), 0, stream>>>(Qb, kvs, kvc, zden, sincos, Out);
}

// Round 4
// 215.383 us; speedup vs baseline: 4.7105x; 2.7323x over previous
//
#include <hip/hip_runtime.h>
#include <hip/hip_bf16.h>

#define BB 4
#define NN 4096
#define DD 512
#define BND (BB*NN)   // 16384

typedef __attribute__((ext_vector_type(8))) short bf16x8;
typedef __attribute__((ext_vector_type(4))) float f32x4;

// ---------- bf16 helpers ----------
__device__ __forceinline__ float b2f(unsigned int u){
    union { unsigned int u; float f; } c; c.u = u << 16; return c.f;
}
__device__ __forceinline__ unsigned short f2b(float f){
    union { float f; unsigned int u; } c; c.f = f;
    unsigned int r = c.u + 0x7fffu + ((c.u >> 16) & 1u);   // RNE
    return (unsigned short)(r >> 16);
}
__device__ __forceinline__ unsigned int pack2(float lo, float hi){
    __hip_bfloat162 h = __float22bfloat162_rn(make_float2(lo, hi));
    return *reinterpret_cast<unsigned int*>(&h);
}
__device__ __forceinline__ void unpack8(uint4 v, float* o){
    o[0]=b2f(v.x & 0xffffu); o[1]=b2f(v.x >> 16);
    o[2]=b2f(v.y & 0xffffu); o[3]=b2f(v.y >> 16);
    o[4]=b2f(v.z & 0xffffu); o[5]=b2f(v.z >> 16);
    o[6]=b2f(v.w & 0xffffu); o[7]=b2f(v.w >> 16);
}

// ---------- sin/cos table ----------
__global__ void k_sincos(float* __restrict__ sc){
    int t = blockIdx.x * 256 + threadIdx.x;
    if (t < NN){
        float idx = 1.5707963267948966f * ((float)(t + 1) / (float)NN);
        sc[t]      = sinf(idx);
        sc[NN + t] = cosf(idx);
    }
}

// ---------- q,k,v = relu?(x @ W^T) via MFMA ----------
// Q written row-major [BND][512]; K,V written TRANSPOSED [512][BND] (packed uint2 stores).
__global__ __launch_bounds__(256) void k_qkv_mfma(
    const float* __restrict__ X,
    const float* __restrict__ Wq,
    const float* __restrict__ Wk,
    const float* __restrict__ Wv,
    unsigned short* __restrict__ Qb,
    unsigned short* __restrict__ Kt,
    unsigned short* __restrict__ Vt)
{
    __shared__ __align__(16) unsigned short As[128][40];
    __shared__ __align__(16) unsigned short Bs[128][40];

    const int which = blockIdx.z;
    const float* W = (which == 0) ? Wq : ((which == 1) ? Wk : Wv);

    const int tid = threadIdx.x;
    const int r0 = blockIdx.x * 128;          // global rows (b*N+n)
    const int c0 = blockIdx.y * 128;          // output dim d
    const int w  = tid >> 6;
    const int l  = tid & 63;
    const int wr = (w >> 1) * 64;
    const int wc = (w & 1) * 64;
    const int lm = l & 15;
    const int lk = (l >> 4) * 8;

    const int srow = tid >> 2;
    const int scol = (tid & 3) * 8;
    const float* xp0 = X + (size_t)(r0 + srow) * DD + scol;
    const float* wp0 = W + (size_t)(c0 + srow) * DD + scol;

    f32x4 acc[4][4];
    #pragma unroll
    for (int i = 0; i < 4; ++i)
        #pragma unroll
        for (int j = 0; j < 4; ++j)
            #pragma unroll
            for (int q = 0; q < 4; ++q) acc[i][j][q] = 0.0f;

    for (int k0 = 0; k0 < DD; k0 += 32){
        const float* xa = xp0 + k0;
        float4 a0 = *reinterpret_cast<const float4*>(xa);
        float4 a1 = *reinterpret_cast<const float4*>(xa + 4);
        float4 a2 = *reinterpret_cast<const float4*>(xa + (size_t)64*DD);
        float4 a3 = *reinterpret_cast<const float4*>(xa + (size_t)64*DD + 4);
        const float* wa = wp0 + k0;
        float4 b0 = *reinterpret_cast<const float4*>(wa);
        float4 b1 = *reinterpret_cast<const float4*>(wa + 4);
        float4 b2 = *reinterpret_cast<const float4*>(wa + (size_t)64*DD);
        float4 b3 = *reinterpret_cast<const float4*>(wa + (size_t)64*DD + 4);
        __syncthreads();
        uint4 st;
        st.x = pack2(a0.x, a0.y); st.y = pack2(a0.z, a0.w);
        st.z = pack2(a1.x, a1.y); st.w = pack2(a1.z, a1.w);
        *reinterpret_cast<uint4*>(&As[srow][scol]) = st;
        st.x = pack2(a2.x, a2.y); st.y = pack2(a2.z, a2.w);
        st.z = pack2(a3.x, a3.y); st.w = pack2(a3.z, a3.w);
        *reinterpret_cast<uint4*>(&As[srow + 64][scol]) = st;
        st.x = pack2(b0.x, b0.y); st.y = pack2(b0.z, b0.w);
        st.z = pack2(b1.x, b1.y); st.w = pack2(b1.z, b1.w);
        *reinterpret_cast<uint4*>(&Bs[srow][scol]) = st;
        st.x = pack2(b2.x, b2.y); st.y = pack2(b2.z, b2.w);
        st.z = pack2(b3.x, b3.y); st.w = pack2(b3.z, b3.w);
        *reinterpret_cast<uint4*>(&Bs[srow + 64][scol]) = st;
        __syncthreads();

        bf16x8 af[4], bfr[4];
        #pragma unroll
        for (int i = 0; i < 4; ++i)
            af[i] = *reinterpret_cast<const bf16x8*>(&As[wr + i*16 + lm][lk]);
        #pragma unroll
        for (int j = 0; j < 4; ++j)
            bfr[j] = *reinterpret_cast<const bf16x8*>(&Bs[wc + j*16 + lm][lk]);
        #pragma unroll
        for (int i = 0; i < 4; ++i)
            #pragma unroll
            for (int j = 0; j < 4; ++j)
                acc[i][j] = __builtin_amdgcn_mfma_f32_16x16x32_bf16(af[i], bfr[j], acc[i][j], 0, 0, 0);
    }

    if (which == 0){
        // row-major Qb with relu
        #pragma unroll
        for (int i = 0; i < 4; ++i){
            #pragma unroll
            for (int q = 0; q < 4; ++q){
                int row = r0 + wr + i*16 + (l >> 4)*4 + q;
                size_t base = (size_t)row * DD + c0 + wc + lm;
                #pragma unroll
                for (int j = 0; j < 4; ++j)
                    Qb[base + j*16] = f2b(fmaxf(acc[i][j][q], 0.0f));
            }
        }
    } else {
        unsigned short* O = (which == 1) ? Kt : Vt;
        const bool relu = (which == 1);
        #pragma unroll
        for (int i = 0; i < 4; ++i){
            int rb = r0 + wr + i*16 + (l >> 4)*4;   // 4 consecutive global rows
            #pragma unroll
            for (int j = 0; j < 4; ++j){
                int d = c0 + wc + j*16 + lm;
                float v0 = acc[i][j][0], v1 = acc[i][j][1], v2 = acc[i][j][2], v3 = acc[i][j][3];
                if (relu){ v0 = fmaxf(v0,0.f); v1 = fmaxf(v1,0.f); v2 = fmaxf(v2,0.f); v3 = fmaxf(v3,0.f); }
                uint2 st;
                st.x = pack2(v0, v1);
                st.y = pack2(v2, v3);
                *reinterpret_cast<uint2*>(O + (size_t)d * BND + rb) = st;
            }
        }
    }
}

// ---------- kvp[b][m][d(sin) | 512+d(cos)] = sum_n v[n,m] * w_n * k[n,d] ----------
// A = Vt rows (m), B = Kt rows (d) scaled by sin/cos at staging. Split-8 over n, atomic f32.
__global__ __launch_bounds__(256) void k_kv_mfma(
    const unsigned short* __restrict__ Vt,
    const unsigned short* __restrict__ Kt,
    const float* __restrict__ sc,
    float* __restrict__ kvp)
{
    __shared__ __align__(16) unsigned short As[128][40];
    __shared__ __align__(16) unsigned short Bsn[128][40];
    __shared__ __align__(16) unsigned short Bcs[128][40];

    const int tid = threadIdx.x;
    const int m0  = blockIdx.x * 128;
    const int dp0 = blockIdx.y * 128;
    const int b   = blockIdx.z >> 3;
    const int sp  = blockIdx.z & 7;
    const int cb  = b * NN + sp * 512;      // column base into Kt/Vt
    const int w  = tid >> 6, l = tid & 63;
    const int wr = (w >> 1) * 64, wc = (w & 1) * 64;
    const int lm = l & 15, lk = (l >> 4) * 8;

    const int srow = tid >> 1;
    const int snh  = (tid & 1) * 16;
    const unsigned short* aP = Vt + (size_t)(m0  + srow) * BND + cb + snh;
    const unsigned short* bP = Kt + (size_t)(dp0 + srow) * BND + cb + snh;

    f32x4 accS[4][4], accC[4][4];
    #pragma unroll
    for (int i = 0; i < 4; ++i)
        #pragma unroll
        for (int j = 0; j < 4; ++j)
            #pragma unroll
            for (int q = 0; q < 4; ++q){ accS[i][j][q] = 0.f; accC[i][j][q] = 0.f; }

    for (int ks = 0; ks < 16; ++ks){
        const int nb = ks * 32;
        uint4 av0 = *reinterpret_cast<const uint4*>(aP + nb);
        uint4 av1 = *reinterpret_cast<const uint4*>(aP + nb + 8);
        uint4 bv0 = *reinterpret_cast<const uint4*>(bP + nb);
        uint4 bv1 = *reinterpret_cast<const uint4*>(bP + nb + 8);
        const int nbase = sp * 512 + nb + snh;  // within-batch n for sc
        float sv[16], cv[16];
        #pragma unroll
        for (int u = 0; u < 16; u += 4){
            float4 s4 = *reinterpret_cast<const float4*>(sc + nbase + u);
            float4 c4 = *reinterpret_cast<const float4*>(sc + NN + nbase + u);
            sv[u]=s4.x; sv[u+1]=s4.y; sv[u+2]=s4.z; sv[u+3]=s4.w;
            cv[u]=c4.x; cv[u+1]=c4.y; cv[u+2]=c4.z; cv[u+3]=c4.w;
        }
        float kf[16];
        unpack8(bv0, kf); unpack8(bv1, kf + 8);
        __syncthreads();
        *reinterpret_cast<uint4*>(&As[srow][snh])     = av0;
        *reinterpret_cast<uint4*>(&As[srow][snh + 8]) = av1;
        uint4 ws, wcs;
        ws.x  = pack2(kf[0]*sv[0],  kf[1]*sv[1]);  ws.y  = pack2(kf[2]*sv[2],  kf[3]*sv[3]);
        ws.z  = pack2(kf[4]*sv[4],  kf[5]*sv[5]);  ws.w  = pack2(kf[6]*sv[6],  kf[7]*sv[7]);
        wcs.x = pack2(kf[0]*cv[0],  kf[1]*cv[1]);  wcs.y = pack2(kf[2]*cv[2],  kf[3]*cv[3]);
        wcs.z = pack2(kf[4]*cv[4],  kf[5]*cv[5]);  wcs.w = pack2(kf[6]*cv[6],  kf[7]*cv[7]);
        *reinterpret_cast<uint4*>(&Bsn[srow][snh]) = ws;
        *reinterpret_cast<uint4*>(&Bcs[srow][snh]) = wcs;
        ws.x  = pack2(kf[8]*sv[8],   kf[9]*sv[9]);   ws.y  = pack2(kf[10]*sv[10], kf[11]*sv[11]);
        ws.z  = pack2(kf[12]*sv[12], kf[13]*sv[13]); ws.w  = pack2(kf[14]*sv[14], kf[15]*sv[15]);
        wcs.x = pack2(kf[8]*cv[8],   kf[9]*cv[9]);   wcs.y = pack2(kf[10]*cv[10], kf[11]*cv[11]);
        wcs.z = pack2(kf[12]*cv[12], kf[13]*cv[13]); wcs.w = pack2(kf[14]*cv[14], kf[15]*cv[15]);
        *reinterpret_cast<uint4*>(&Bsn[srow][snh + 8]) = ws;
        *reinterpret_cast<uint4*>(&Bcs[srow][snh + 8]) = wcs;
        __syncthreads();

        bf16x8 af[4], bs[4], bc[4];
        #pragma unroll
        for (int i = 0; i < 4; ++i)
            af[i] = *reinterpret_cast<const bf16x8*>(&As[wr + i*16 + lm][lk]);
        #pragma unroll
        for (int j = 0; j < 4; ++j){
            bs[j] = *reinterpret_cast<const bf16x8*>(&Bsn[wc + j*16 + lm][lk]);
            bc[j] = *reinterpret_cast<const bf16x8*>(&Bcs[wc + j*16 + lm][lk]);
        }
        #pragma unroll
        for (int i = 0; i < 4; ++i)
            #pragma unroll
            for (int j = 0; j < 4; ++j){
                accS[i][j] = __builtin_amdgcn_mfma_f32_16x16x32_bf16(af[i], bs[j], accS[i][j], 0, 0, 0);
                accC[i][j] = __builtin_amdgcn_mfma_f32_16x16x32_bf16(af[i], bc[j], accC[i][j], 0, 0, 0);
            }
    }

    #pragma unroll
    for (int i = 0; i < 4; ++i){
        #pragma unroll
        for (int q = 0; q < 4; ++q){
            int m = m0 + wr + i*16 + (l >> 4)*4 + q;
            float* rowp = kvp + ((size_t)b*512 + m) * 1024;
            #pragma unroll
            for (int j = 0; j < 4; ++j){
                int d = dp0 + wc + j*16 + lm;
                atomicAdd(rowp + d,       accS[i][j][q]);
                atomicAdd(rowp + 512 + d, accC[i][j][q]);
            }
        }
    }
}

// ---------- ksum[b][d]=sum_n sin_n k; ksum[b][512+d]=cos version ----------
__global__ __launch_bounds__(256) void k_ksum(
    const unsigned short* __restrict__ Kt,
    const float* __restrict__ sc, float* __restrict__ ksum)
{
    int b = blockIdx.y;
    int d = blockIdx.x * 4 + (threadIdx.x >> 6);
    int l = threadIdx.x & 63;
    const unsigned short* row = Kt + (size_t)d * BND + b * NN;
    float ss = 0.f, cc = 0.f;
    for (int c0 = 0; c0 < NN; c0 += 512){
        int col = c0 + l * 8;
        uint4 kv4 = *reinterpret_cast<const uint4*>(row + col);
        float kf[8]; unpack8(kv4, kf);
        float4 sA = *reinterpret_cast<const float4*>(sc + col);
        float4 sB = *reinterpret_cast<const float4*>(sc + col + 4);
        float4 cA = *reinterpret_cast<const float4*>(sc + NN + col);
        float4 cB = *reinterpret_cast<const float4*>(sc + NN + col + 4);
        ss = fmaf(kf[0],sA.x, fmaf(kf[1],sA.y, fmaf(kf[2],sA.z, fmaf(kf[3],sA.w, ss))));
        ss = fmaf(kf[4],sB.x, fmaf(kf[5],sB.y, fmaf(kf[6],sB.z, fmaf(kf[7],sB.w, ss))));
        cc = fmaf(kf[0],cA.x, fmaf(kf[1],cA.y, fmaf(kf[2],cA.z, fmaf(kf[3],cA.w, cc))));
        cc = fmaf(kf[4],cB.x, fmaf(kf[5],cB.y, fmaf(kf[6],cB.z, fmaf(kf[7],cB.w, cc))));
    }
    #pragma unroll
    for (int off = 32; off; off >>= 1){ ss += __shfl_xor(ss, off); cc += __shfl_xor(cc, off); }
    if (l == 0){
        ksum[b*1024 + d]       = ss;
        ksum[b*1024 + 512 + d] = cc;
    }
}

// ---------- z[row] = 1/max(sin_n*(q.ksum_s) + cos_n*(q.ksum_c), 1e-6) ----------
__global__ __launch_bounds__(256) void k_z(
    const unsigned short* __restrict__ Qb,
    const float* __restrict__ ksum, const float* __restrict__ sc,
    float* __restrict__ zden)
{
    int row  = blockIdx.x * 4 + (threadIdx.x >> 6);
    int lane = threadIdx.x & 63;
    int b = row >> 12, n = row & (NN - 1);
    uint4 qv = *reinterpret_cast<const uint4*>(Qb + (size_t)row * DD + lane * 8);
    float qf[8]; unpack8(qv, qf);
    const float* kss = ksum + (size_t)b*1024 + lane*8;
    const float* ksc = kss + 512;
    float ps = 0.f, pc = 0.f;
    #pragma unroll
    for (int u = 0; u < 8; ++u){ ps = fmaf(qf[u], kss[u], ps); pc = fmaf(qf[u], ksc[u], pc); }
    #pragma unroll
    for (int off = 32; off; off >>= 1){ ps += __shfl_xor(ps, off); pc += __shfl_xor(pc, off); }
    if (lane == 0){
        float den = sc[n]*ps + sc[NN+n]*pc;
        zden[row] = 1.0f / fmaxf(den, 1e-6f);
    }
}

// ---------- out[n][m] = z*(sin*q@kvs + cos*q@kvc), scrambled write ----------
__global__ __launch_bounds__(256) void k_out_mfma(
    const unsigned short* __restrict__ Qb,
    const float* __restrict__ kvp,
    const float* __restrict__ zden, const float* __restrict__ sc,
    float* __restrict__ Out)
{
    __shared__ __align__(16) unsigned short As[128][40];
    __shared__ __align__(16) unsigned short Bsn[128][40];
    __shared__ __align__(16) unsigned short Bcs[128][40];

    const int tid = threadIdx.x;
    const int r0 = blockIdx.x * 128;     // global rows
    const int m0 = blockIdx.y * 128;     // output cols
    const int b  = r0 >> 12;
    const int w  = tid >> 6, l = tid & 63;
    const int wr = (w >> 1) * 64, wc = (w & 1) * 64;
    const int lm = l & 15, lk = (l >> 4) * 8;

    const int srow = tid >> 1;
    const int snh  = (tid & 1) * 16;
    const unsigned short* aP = Qb + (size_t)(r0 + srow) * DD + snh;
    const float* kvP = kvp + ((size_t)b*512 + m0 + srow) * 1024 + snh;

    f32x4 accS[4][4], accC[4][4];
    #pragma unroll
    for (int i = 0; i < 4; ++i)
        #pragma unroll
        for (int j = 0; j < 4; ++j)
            #pragma unroll
            for (int q = 0; q < 4; ++q){ accS[i][j][q] = 0.f; accC[i][j][q] = 0.f; }

    for (int ks = 0; ks < 16; ++ks){
        const int k0 = ks * 32;
        uint4 qa0 = *reinterpret_cast<const uint4*>(aP + k0);
        uint4 qa1 = *reinterpret_cast<const uint4*>(aP + k0 + 8);
        float4 f0 = *reinterpret_cast<const float4*>(kvP + k0);
        float4 f1 = *reinterpret_cast<const float4*>(kvP + k0 + 4);
        float4 f2 = *reinterpret_cast<const float4*>(kvP + k0 + 8);
        float4 f3 = *reinterpret_cast<const float4*>(kvP + k0 + 12);
        float4 g0 = *reinterpret_cast<const float4*>(kvP + 512 + k0);
        float4 g1 = *reinterpret_cast<const float4*>(kvP + 512 + k0 + 4);
        float4 g2 = *reinterpret_cast<const float4*>(kvP + 512 + k0 + 8);
        float4 g3 = *reinterpret_cast<const float4*>(kvP + 512 + k0 + 12);
        __syncthreads();
        *reinterpret_cast<uint4*>(&As[srow][snh])     = qa0;
        *reinterpret_cast<uint4*>(&As[srow][snh + 8]) = qa1;
        uint4 st;
        st.x = pack2(f0.x, f0.y); st.y = pack2(f0.z, f0.w);
        st.z = pack2(f1.x, f1.y); st.w = pack2(f1.z, f1.w);
        *reinterpret_cast<uint4*>(&Bsn[srow][snh]) = st;
        st.x = pack2(f2.x, f2.y); st.y = pack2(f2.z, f2.w);
        st.z = pack2(f3.x, f3.y); st.w = pack2(f3.z, f3.w);
        *reinterpret_cast<uint4*>(&Bsn[srow][snh + 8]) = st;
        st.x = pack2(g0.x, g0.y); st.y = pack2(g0.z, g0.w);
        st.z = pack2(g1.x, g1.y); st.w = pack2(g1.z, g1.w);
        *reinterpret_cast<uint4*>(&Bcs[srow][snh]) = st;
        st.x = pack2(g2.x, g2.y); st.y = pack2(g2.z, g2.w);
        st.z = pack2(g3.x, g3.y); st.w = pack2(g3.z, g3.w);
        *reinterpret_cast<uint4*>(&Bcs[srow][snh + 8]) = st;
        __syncthreads();

        bf16x8 af[4], bs[4], bc[4];
        #pragma unroll
        for (int i = 0; i < 4; ++i)
            af[i] = *reinterpret_cast<const bf16x8*>(&As[wr + i*16 + lm][lk]);
        #pragma unroll
        for (int j = 0; j < 4; ++j){
            bs[j] = *reinterpret_cast<const bf16x8*>(&Bsn[wc + j*16 + lm][lk]);
            bc[j] = *reinterpret_cast<const bf16x8*>(&Bcs[wc + j*16 + lm][lk]);
        }
        #pragma unroll
        for (int i = 0; i < 4; ++i)
            #pragma unroll
            for (int j = 0; j < 4; ++j){
                accS[i][j] = __builtin_amdgcn_mfma_f32_16x16x32_bf16(af[i], bs[j], accS[i][j], 0, 0, 0);
                accC[i][j] = __builtin_amdgcn_mfma_f32_16x16x32_bf16(af[i], bc[j], accC[i][j], 0, 0, 0);
            }
    }

    #pragma unroll
    for (int i = 0; i < 4; ++i){
        #pragma unroll
        for (int q = 0; q < 4; ++q){
            int grow = r0 + wr + i*16 + (l >> 4)*4 + q;
            int n = grow & (NN - 1);
            float z  = zden[grow];
            float sn = sc[n], cn = sc[NN + n];
            int hh = n >> 9;
            int ttb = (n & 511) * 8;
            #pragma unroll
            for (int j = 0; j < 4; ++j){
                int m = m0 + wc + j*16 + lm;
                int tt = ttb + (m >> 6);
                float v = (sn*accS[i][j][q] + cn*accC[i][j][q]) * z;
                Out[((size_t)b*NN + tt) * DD + hh*64 + (m & 63)] = v;
            }
        }
    }
}

extern "C" void kernel_launch(void* const* d_in, const int* in_sizes, int n_in,
                              void* d_out, int out_size, void* d_ws, size_t ws_size,
                              hipStream_t stream)
{
    const float* X  = (const float*)d_in[0];
    const float* Wq = (const float*)d_in[1];
    const float* Wk = (const float*)d_in[2];
    const float* Wv = (const float*)d_in[3];
    float* Out = (float*)d_out;

    char* p = (char*)d_ws;
    float* sincos = (float*)p; p += (size_t)2*NN*sizeof(float);
    float* kvp    = (float*)p; p += (size_t)BB*512*1024*sizeof(float);
    float* ksum   = (float*)p; p += (size_t)BB*1024*sizeof(float);
    float* zden   = (float*)p; p += (size_t)BND*sizeof(float);
    unsigned short* Qb = (unsigned short*)p; p += (size_t)BND*DD*2;
    unsigned short* Kt = (unsigned short*)p; p += (size_t)DD*BND*2;
    unsigned short* Vt = (unsigned short*)p; p += (size_t)DD*BND*2;

    // only kvp needs zeroing (atomic accumulation)
    hipMemsetAsync(kvp, 0, (size_t)BB*512*1024*sizeof(float), stream);

    k_sincos  <<<dim3(16), dim3(256), 0, stream>>>(sincos);
    k_qkv_mfma<<<dim3(BND/128, DD/128, 3), dim3(256), 0, stream>>>(X, Wq, Wk, Wv, Qb, Kt, Vt);
    k_kv_mfma <<<dim3(4, 4, 32), dim3(256), 0, stream>>>(Vt, Kt, sincos, kvp);
    k_ksum    <<<dim3(128, 4), dim3(256), 0, stream>>>(Kt, sincos, ksum);
    k_z       <<<dim3(BND/4), dim3(256), 0, stream>>>(Qb, ksum, sincos, zden);
    k_out_mfma<<<dim3(BND/128, 4), dim3(256), 0, stream>>>(Qb, kvp, zden, sincos, Out);
}

// Round 5
// 205.105 us; speedup vs baseline: 4.9466x; 1.0501x over previous
//
#include <hip/hip_runtime.h>
#include <hip/hip_bf16.h>

#define BB 4
#define NN 4096
#define DD 512
#define BND (BB*NN)   // 16384

typedef __attribute__((ext_vector_type(8))) short bf16x8;
typedef __attribute__((ext_vector_type(4))) float f32x4;

// ---------- bf16 helpers ----------
__device__ __forceinline__ float b2f(unsigned int u){
    union { unsigned int u; float f; } c; c.u = u << 16; return c.f;
}
__device__ __forceinline__ unsigned short f2b(float f){
    union { float f; unsigned int u; } c; c.f = f;
    unsigned int r = c.u + 0x7fffu + ((c.u >> 16) & 1u);   // RNE
    return (unsigned short)(r >> 16);
}
__device__ __forceinline__ unsigned int pack2(float lo, float hi){
    __hip_bfloat162 h = __float22bfloat162_rn(make_float2(lo, hi));
    return *reinterpret_cast<unsigned int*>(&h);
}
__device__ __forceinline__ void unpack8(uint4 v, float* o){
    o[0]=b2f(v.x & 0xffffu); o[1]=b2f(v.x >> 16);
    o[2]=b2f(v.y & 0xffffu); o[3]=b2f(v.y >> 16);
    o[4]=b2f(v.z & 0xffffu); o[5]=b2f(v.z >> 16);
    o[6]=b2f(v.w & 0xffffu); o[7]=b2f(v.w >> 16);
}

// async global->LDS, 16B per lane; lds dest must be wave-uniform base + lane*16
__device__ __forceinline__ void gload16(const void* g, void* l){
    __builtin_amdgcn_global_load_lds(
        (const __attribute__((address_space(1))) unsigned int*)g,
        (__attribute__((address_space(3))) unsigned int*)l,
        16, 0, 0);
}

// ---------- sin/cos table ----------
__global__ void k_sincos(float* __restrict__ sc){
    int t = blockIdx.x * 256 + threadIdx.x;
    if (t < NN){
        float idx = 1.5707963267948966f * ((float)(t + 1) / (float)NN);
        sc[t]      = sinf(idx);
        sc[NN + t] = cosf(idx);
    }
}

// ---------- fp32 -> bf16 bulk convert (n8 = count/8) ----------
__global__ void k_cvt(const float* __restrict__ in, unsigned short* __restrict__ out, int n8){
    int t = blockIdx.x * 256 + threadIdx.x;
    if (t < n8){
        float4 a = reinterpret_cast<const float4*>(in)[t*2];
        float4 b = reinterpret_cast<const float4*>(in)[t*2+1];
        uint4 st;
        st.x = pack2(a.x, a.y); st.y = pack2(a.z, a.w);
        st.z = pack2(b.x, b.y); st.w = pack2(b.z, b.w);
        reinterpret_cast<uint4*>(out)[t] = st;
    }
}

// ---------- q,k,v GEMM: 128x128 tile, gload_lds staging, linear LDS ----------
// which 0: Qb row-major (relu); 1: Kts/Ktc transposed (relu, pre-scaled); 2: Vt transposed
__global__ __launch_bounds__(256) void k_qkv(
    const unsigned short* __restrict__ Xb,
    const unsigned short* __restrict__ Wqb,
    const unsigned short* __restrict__ Wkb,
    const unsigned short* __restrict__ Wvb,
    const float* __restrict__ sc,
    unsigned short* __restrict__ Qb,
    unsigned short* __restrict__ Kts,
    unsigned short* __restrict__ Ktc,
    unsigned short* __restrict__ Vt)
{
    __shared__ __align__(16) unsigned short As[128*32];
    __shared__ __align__(16) unsigned short Bs[128*32];

    const int which = blockIdx.z;
    const unsigned short* W = (which == 0) ? Wqb : ((which == 1) ? Wkb : Wvb);

    const int tid = threadIdx.x;
    const int r0 = blockIdx.x * 128;
    const int c0 = blockIdx.y * 128;
    const int w  = tid >> 6, l = tid & 63;
    const int wr = (w >> 1) * 64, wc = (w & 1) * 64;
    const int lm = l & 15, lq = l >> 4, lk = lq * 8;

    const int grow = w * 16 + (l >> 2);
    const int gcol = (l & 3) * 8;
    const unsigned short* aP = Xb + (size_t)(r0 + grow) * DD + gcol;
    const unsigned short* bP = W  + (size_t)(c0 + grow) * DD + gcol;
    unsigned short* lA0 = &As[w * 512];
    unsigned short* lA1 = &As[2048 + w * 512];
    unsigned short* lB0 = &Bs[w * 512];
    unsigned short* lB1 = &Bs[2048 + w * 512];

    f32x4 acc[4][4];
    #pragma unroll
    for (int i = 0; i < 4; ++i)
        #pragma unroll
        for (int j = 0; j < 4; ++j)
            #pragma unroll
            for (int q = 0; q < 4; ++q) acc[i][j][q] = 0.0f;

    for (int k0 = 0; k0 < DD; k0 += 32){
        __syncthreads();
        gload16(aP + k0,                    lA0);
        gload16(aP + (size_t)64*DD + k0,    lA1);
        gload16(bP + k0,                    lB0);
        gload16(bP + (size_t)64*DD + k0,    lB1);
        __syncthreads();
        bf16x8 af[4], bf[4];
        #pragma unroll
        for (int i = 0; i < 4; ++i)
            af[i] = *reinterpret_cast<const bf16x8*>(&As[(wr + i*16 + lm)*32 + lk]);
        #pragma unroll
        for (int j = 0; j < 4; ++j)
            bf[j] = *reinterpret_cast<const bf16x8*>(&Bs[(wc + j*16 + lm)*32 + lk]);
        #pragma unroll
        for (int i = 0; i < 4; ++i)
            #pragma unroll
            for (int j = 0; j < 4; ++j)
                acc[i][j] = __builtin_amdgcn_mfma_f32_16x16x32_bf16(af[i], bf[j], acc[i][j], 0, 0, 0);
    }

    if (which == 0){
        #pragma unroll
        for (int i = 0; i < 4; ++i){
            #pragma unroll
            for (int q = 0; q < 4; ++q){
                int row = r0 + wr + i*16 + lq*4 + q;
                size_t base = (size_t)row * DD + c0 + wc + lm;
                #pragma unroll
                for (int j = 0; j < 4; ++j)
                    Qb[base + j*16] = f2b(fmaxf(acc[i][j][q], 0.0f));
            }
        }
    } else if (which == 1){
        #pragma unroll
        for (int i = 0; i < 4; ++i){
            int rb = r0 + wr + i*16 + lq*4;       // 4 consecutive global rows
            int n  = rb & (NN - 1);
            float4 s4 = *reinterpret_cast<const float4*>(sc + n);
            float4 c4 = *reinterpret_cast<const float4*>(sc + NN + n);
            #pragma unroll
            for (int j = 0; j < 4; ++j){
                int d = c0 + wc + j*16 + lm;
                float v0 = fmaxf(acc[i][j][0], 0.f), v1 = fmaxf(acc[i][j][1], 0.f);
                float v2 = fmaxf(acc[i][j][2], 0.f), v3 = fmaxf(acc[i][j][3], 0.f);
                uint2 stS, stC;
                stS.x = pack2(v0*s4.x, v1*s4.y); stS.y = pack2(v2*s4.z, v3*s4.w);
                stC.x = pack2(v0*c4.x, v1*c4.y); stC.y = pack2(v2*c4.z, v3*c4.w);
                *reinterpret_cast<uint2*>(Kts + (size_t)d * BND + rb) = stS;
                *reinterpret_cast<uint2*>(Ktc + (size_t)d * BND + rb) = stC;
            }
        }
    } else {
        #pragma unroll
        for (int i = 0; i < 4; ++i){
            int rb = r0 + wr + i*16 + lq*4;
            #pragma unroll
            for (int j = 0; j < 4; ++j){
                int d = c0 + wc + j*16 + lm;
                uint2 st;
                st.x = pack2(acc[i][j][0], acc[i][j][1]);
                st.y = pack2(acc[i][j][2], acc[i][j][3]);
                *reinterpret_cast<uint2*>(Vt + (size_t)d * BND + rb) = st;
            }
        }
    }
}

// ---------- kvp[b][m][d | 512+d] += sum_n v[n,m]*{Kts,Ktc}[d,n] ----------
// Tiles: 128 (m) x 64 (d), split-8 over n. Pure-copy gload_lds staging.
__global__ __launch_bounds__(256) void k_kv(
    const unsigned short* __restrict__ Vt,
    const unsigned short* __restrict__ Kts,
    const unsigned short* __restrict__ Ktc,
    float* __restrict__ kvp)
{
    __shared__ __align__(16) unsigned short As[128*32];
    __shared__ __align__(16) unsigned short Bs[64*32];
    __shared__ __align__(16) unsigned short Bc[64*32];

    const int tid = threadIdx.x;
    const int m0  = blockIdx.x * 128;
    const int dp0 = blockIdx.y * 64;
    const int b   = blockIdx.z >> 3;
    const int sp  = blockIdx.z & 7;
    const int cb  = b * NN + sp * 512;    // 512-wide n chunk
    const int w  = tid >> 6, l = tid & 63;
    const int wr = (w >> 1) * 64, wc = (w & 1) * 32;
    const int lm = l & 15, lq = l >> 4, lk = lq * 8;

    const int grow = w * 16 + (l >> 2);
    const int gcol = (l & 3) * 8;
    const unsigned short* aP  = Vt  + (size_t)(m0  + grow) * BND + cb + gcol;
    const unsigned short* bPs = Kts + (size_t)(dp0 + grow) * BND + cb + gcol;
    const unsigned short* bPc = Ktc + (size_t)(dp0 + grow) * BND + cb + gcol;
    unsigned short* lA0 = &As[w * 512];
    unsigned short* lA1 = &As[2048 + w * 512];
    unsigned short* lBs = &Bs[w * 512];
    unsigned short* lBc = &Bc[w * 512];

    f32x4 accS[4][2], accC[4][2];
    #pragma unroll
    for (int i = 0; i < 4; ++i)
        #pragma unroll
        for (int j = 0; j < 2; ++j)
            #pragma unroll
            for (int q = 0; q < 4; ++q){ accS[i][j][q] = 0.f; accC[i][j][q] = 0.f; }

    for (int nb = 0; nb < 512; nb += 32){
        __syncthreads();
        gload16(aP + nb,                     lA0);
        gload16(aP + (size_t)64*BND + nb,    lA1);
        gload16(bPs + nb,                    lBs);
        gload16(bPc + nb,                    lBc);
        __syncthreads();
        bf16x8 af[4], bs[2], bc[2];
        #pragma unroll
        for (int i = 0; i < 4; ++i)
            af[i] = *reinterpret_cast<const bf16x8*>(&As[(wr + i*16 + lm)*32 + lk]);
        #pragma unroll
        for (int j = 0; j < 2; ++j){
            bs[j] = *reinterpret_cast<const bf16x8*>(&Bs[(wc + j*16 + lm)*32 + lk]);
            bc[j] = *reinterpret_cast<const bf16x8*>(&Bc[(wc + j*16 + lm)*32 + lk]);
        }
        #pragma unroll
        for (int i = 0; i < 4; ++i)
            #pragma unroll
            for (int j = 0; j < 2; ++j){
                accS[i][j] = __builtin_amdgcn_mfma_f32_16x16x32_bf16(af[i], bs[j], accS[i][j], 0, 0, 0);
                accC[i][j] = __builtin_amdgcn_mfma_f32_16x16x32_bf16(af[i], bc[j], accC[i][j], 0, 0, 0);
            }
    }

    #pragma unroll
    for (int i = 0; i < 4; ++i){
        #pragma unroll
        for (int q = 0; q < 4; ++q){
            int m = m0 + wr + i*16 + lq*4 + q;
            float* rowp = kvp + ((size_t)b*512 + m) * 1024;
            #pragma unroll
            for (int j = 0; j < 2; ++j){
                int d = dp0 + wc + j*16 + lm;
                atomicAdd(rowp + d,       accS[i][j][q]);
                atomicAdd(rowp + 512 + d, accC[i][j][q]);
            }
        }
    }
}

// ---------- ksum: row-sums of pre-scaled Kts/Ktc ----------
__global__ __launch_bounds__(256) void k_ksum(
    const unsigned short* __restrict__ Kts,
    const unsigned short* __restrict__ Ktc,
    float* __restrict__ ksum)
{
    int b = blockIdx.y;
    int d = blockIdx.x * 4 + (threadIdx.x >> 6);
    int l = threadIdx.x & 63;
    const unsigned short* rs = Kts + (size_t)d * BND + b * NN;
    const unsigned short* rc = Ktc + (size_t)d * BND + b * NN;
    float ss = 0.f, cc = 0.f;
    for (int c0 = 0; c0 < NN; c0 += 512){
        int col = c0 + l * 8;
        float f[8];
        unpack8(*reinterpret_cast<const uint4*>(rs + col), f);
        #pragma unroll
        for (int u = 0; u < 8; ++u) ss += f[u];
        unpack8(*reinterpret_cast<const uint4*>(rc + col), f);
        #pragma unroll
        for (int u = 0; u < 8; ++u) cc += f[u];
    }
    #pragma unroll
    for (int off = 32; off; off >>= 1){ ss += __shfl_xor(ss, off); cc += __shfl_xor(cc, off); }
    if (l == 0){
        ksum[b*1024 + d]       = ss;
        ksum[b*1024 + 512 + d] = cc;
    }
}

// ---------- z[row] ----------
__global__ __launch_bounds__(256) void k_z(
    const unsigned short* __restrict__ Qb,
    const float* __restrict__ ksum, const float* __restrict__ sc,
    float* __restrict__ zden)
{
    int row  = blockIdx.x * 4 + (threadIdx.x >> 6);
    int lane = threadIdx.x & 63;
    int b = row >> 12, n = row & (NN - 1);
    uint4 qv = *reinterpret_cast<const uint4*>(Qb + (size_t)row * DD + lane * 8);
    float qf[8]; unpack8(qv, qf);
    const float* kss = ksum + (size_t)b*1024 + lane*8;
    const float* ksc = kss + 512;
    float ps = 0.f, pc = 0.f;
    #pragma unroll
    for (int u = 0; u < 8; ++u){ ps = fmaf(qf[u], kss[u], ps); pc = fmaf(qf[u], ksc[u], pc); }
    #pragma unroll
    for (int off = 32; off; off >>= 1){ ps += __shfl_xor(ps, off); pc += __shfl_xor(pc, off); }
    if (lane == 0){
        float den = sc[n]*ps + sc[NN+n]*pc;
        zden[row] = 1.0f / fmaxf(den, 1e-6f);
    }
}

// ---------- out = z*(sin*q@kvs + cos*q@kvc), scrambled write ----------
__global__ __launch_bounds__(256) void k_out(
    const unsigned short* __restrict__ Qb,
    const unsigned short* __restrict__ kvb,
    const float* __restrict__ zden, const float* __restrict__ sc,
    float* __restrict__ Out)
{
    __shared__ __align__(16) unsigned short As[128*32];
    __shared__ __align__(16) unsigned short Bs[128*32];
    __shared__ __align__(16) unsigned short Bc[128*32];

    const int tid = threadIdx.x;
    const int r0 = blockIdx.x * 128;
    const int m0 = blockIdx.y * 128;
    const int b  = r0 >> 12;
    const int w  = tid >> 6, l = tid & 63;
    const int wr = (w >> 1) * 64, wc = (w & 1) * 64;
    const int lm = l & 15, lq = l >> 4, lk = lq * 8;

    const int grow = w * 16 + (l >> 2);
    const int gcol = (l & 3) * 8;
    const unsigned short* aP = Qb + (size_t)(r0 + grow) * DD + gcol;
    const unsigned short* bP = kvb + ((size_t)b*512 + m0 + grow) * 1024 + gcol;
    unsigned short* lA0 = &As[w * 512];
    unsigned short* lA1 = &As[2048 + w * 512];
    unsigned short* lBs0 = &Bs[w * 512];
    unsigned short* lBs1 = &Bs[2048 + w * 512];
    unsigned short* lBc0 = &Bc[w * 512];
    unsigned short* lBc1 = &Bc[2048 + w * 512];

    f32x4 accS[4][4], accC[4][4];
    #pragma unroll
    for (int i = 0; i < 4; ++i)
        #pragma unroll
        for (int j = 0; j < 4; ++j)
            #pragma unroll
            for (int q = 0; q < 4; ++q){ accS[i][j][q] = 0.f; accC[i][j][q] = 0.f; }

    for (int k0 = 0; k0 < DD; k0 += 32){
        __syncthreads();
        gload16(aP + k0,                      lA0);
        gload16(aP + (size_t)64*DD + k0,      lA1);
        gload16(bP + k0,                      lBs0);
        gload16(bP + (size_t)64*1024 + k0,    lBs1);
        gload16(bP + 512 + k0,                lBc0);
        gload16(bP + (size_t)64*1024 + 512 + k0, lBc1);
        __syncthreads();
        bf16x8 af[4], bs[4], bc[4];
        #pragma unroll
        for (int i = 0; i < 4; ++i)
            af[i] = *reinterpret_cast<const bf16x8*>(&As[(wr + i*16 + lm)*32 + lk]);
        #pragma unroll
        for (int j = 0; j < 4; ++j){
            bs[j] = *reinterpret_cast<const bf16x8*>(&Bs[(wc + j*16 + lm)*32 + lk]);
            bc[j] = *reinterpret_cast<const bf16x8*>(&Bc[(wc + j*16 + lm)*32 + lk]);
        }
        #pragma unroll
        for (int i = 0; i < 4; ++i)
            #pragma unroll
            for (int j = 0; j < 4; ++j){
                accS[i][j] = __builtin_amdgcn_mfma_f32_16x16x32_bf16(af[i], bs[j], accS[i][j], 0, 0, 0);
                accC[i][j] = __builtin_amdgcn_mfma_f32_16x16x32_bf16(af[i], bc[j], accC[i][j], 0, 0, 0);
            }
    }

    #pragma unroll
    for (int i = 0; i < 4; ++i){
        #pragma unroll
        for (int q = 0; q < 4; ++q){
            int grow2 = r0 + wr + i*16 + lq*4 + q;
            int n = grow2 & (NN - 1);
            float z  = zden[grow2];
            float sn = sc[n], cn = sc[NN + n];
            int hh = n >> 9;
            int ttb = (n & 511) * 8;
            #pragma unroll
            for (int j = 0; j < 4; ++j){
                int m = m0 + wc + j*16 + lm;
                int tt = ttb + (m >> 6);
                float v = (sn*accS[i][j][q] + cn*accC[i][j][q]) * z;
                Out[((size_t)b*NN + tt) * DD + hh*64 + (m & 63)] = v;
            }
        }
    }
}

extern "C" void kernel_launch(void* const* d_in, const int* in_sizes, int n_in,
                              void* d_out, int out_size, void* d_ws, size_t ws_size,
                              hipStream_t stream)
{
    const float* X  = (const float*)d_in[0];
    const float* Wq = (const float*)d_in[1];
    const float* Wk = (const float*)d_in[2];
    const float* Wv = (const float*)d_in[3];
    float* Out = (float*)d_out;

    char* p = (char*)d_ws;
    float* sincos = (float*)p; p += (size_t)2*NN*sizeof(float);
    float* kvp    = (float*)p; p += (size_t)BB*512*1024*sizeof(float);   // 8 MB
    float* ksum   = (float*)p; p += (size_t)BB*1024*sizeof(float);
    float* zden   = (float*)p; p += (size_t)BND*sizeof(float);
    unsigned short* Xb  = (unsigned short*)p; p += (size_t)BND*DD*2;
    unsigned short* Wqb = (unsigned short*)p; p += (size_t)DD*DD*2;
    unsigned short* Wkb = (unsigned short*)p; p += (size_t)DD*DD*2;
    unsigned short* Wvb = (unsigned short*)p; p += (size_t)DD*DD*2;
    unsigned short* Qb  = (unsigned short*)p; p += (size_t)BND*DD*2;
    unsigned short* Kts = (unsigned short*)p; p += (size_t)DD*BND*2;
    unsigned short* Ktc = (unsigned short*)p; p += (size_t)DD*BND*2;
    unsigned short* Vt  = (unsigned short*)p; p += (size_t)DD*BND*2;
    unsigned short* kvb = (unsigned short*)p; p += (size_t)BB*512*1024*2;

    hipMemsetAsync(kvp, 0, (size_t)BB*512*1024*sizeof(float), stream);

    k_sincos<<<dim3(16), dim3(256), 0, stream>>>(sincos);
    k_cvt   <<<dim3(4096), dim3(256), 0, stream>>>(X,  Xb,  BND*DD/8);
    k_cvt   <<<dim3(128),  dim3(256), 0, stream>>>(Wq, Wqb, DD*DD/8);
    k_cvt   <<<dim3(128),  dim3(256), 0, stream>>>(Wk, Wkb, DD*DD/8);
    k_cvt   <<<dim3(128),  dim3(256), 0, stream>>>(Wv, Wvb, DD*DD/8);
    k_qkv   <<<dim3(BND/128, DD/128, 3), dim3(256), 0, stream>>>(Xb, Wqb, Wkb, Wvb, sincos, Qb, Kts, Ktc, Vt);
    k_kv    <<<dim3(4, 8, 32), dim3(256), 0, stream>>>(Vt, Kts, Ktc, kvp);
    k_ksum  <<<dim3(128, 4), dim3(256), 0, stream>>>(Kts, Ktc, ksum);
    k_z     <<<dim3(BND/4), dim3(256), 0, stream>>>(Qb, ksum, sincos, zden);
    k_cvt   <<<dim3(1024), dim3(256), 0, stream>>>(kvp, kvb, BB*512*1024/8);
    k_out   <<<dim3(BND/128, 4), dim3(256), 0, stream>>>(Qb, kvb, zden, sincos, Out);
}